// Round 13
// baseline (406.020 us; speedup 1.0000x reference)
//
#include <hip/hip_runtime.h>
#include <math.h>

// Round 13: chunked-persistent blocks -- amortize the LDS fill.
// R12 (125.3us): VALU 56%, occ 40%, conflicts 10.4M. Remaining top cost:
// every one of 16384 blocks re-reads the 33.4KB row slab from L2 (547MB L2
// traffic) + ~17 fill ops/point. Fix: 2048 blocks, each owns a contiguous
// 2048-point chunk and loops 8x256 -- fill runs once per block (8x less),
// L2 re-reads 547->68MB. Compute path byte-identical to r12
// (fp16 rows L0-3 in LDS, fp16 cells L4-7, pk-fp16 lerp, dot2 MLP).

typedef float    v2f __attribute__((ext_vector_type(2)));
typedef _Float16 h2  __attribute__((ext_vector_type(2)));
typedef __fp16   hf2 __attribute__((ext_vector_type(2)));   // builtin ABI type

struct EncParams { float scale[8]; };

__constant__ constexpr int SIDE[8]   = {9, 11, 13, 16, 19, 23, 28, 33};
__constant__ constexpr int ROWOFF[8] = {0, 729, 2060, 4257, 8353, 15212, 27379, 49331};
__constant__ constexpr int CS[8]     = {8, 10, 12, 15, 18, 22, 27, 32};
// fine-level cell bases, rebased to 0 at level 4
__constant__ constexpr int CBF[8]    = {0, 0, 0, 0, 0, 5832, 16480, 36163};
#define NROWS_L  8353    // rows of levels 0..3 (= ROWOFF[4]); 33,412 B in LDS
#define NCELLS_F 68931   // cells of levels 4..7

__device__ __forceinline__ unsigned int pack2h(float a, float b) {
    _Float16 ha = (_Float16)a, hb = (_Float16)b;
    unsigned short ua = __builtin_bit_cast(unsigned short, ha);
    unsigned short ub = __builtin_bit_cast(unsigned short, hb);
    return (unsigned int)ua | ((unsigned int)ub << 16);
}
__device__ __forceinline__ h2 as_h2(unsigned int u) {
    return __builtin_bit_cast(h2, u);
}
__device__ __forceinline__ h2 lerp_h2(h2 a, h2 b, h2 r) {
    return a + r * (b - a);   // v_pk_sub/fma_f16
}
__device__ __forceinline__ h2 pkrtz(float a, float b) {
#if __has_builtin(__builtin_amdgcn_cvt_pkrtz)
    return __builtin_bit_cast(h2, __builtin_amdgcn_cvt_pkrtz(a, b));  // 1 op
#else
    return (h2){(_Float16)a, (_Float16)b};
#endif
}
__device__ __forceinline__ float dot2f(h2 a, h2 b, float c) {
#if __has_builtin(__builtin_amdgcn_fdot2)
    return __builtin_amdgcn_fdot2(__builtin_bit_cast(hf2, a),
                                  __builtin_bit_cast(hf2, b), c, false);
#else
    return c + (float)a.x * (float)b.x + (float)a.y * (float)b.y;
#endif
}

// ---- combined build: fp16 rows (levels 0..3) + fp16 cells (levels 4..7) ----
__global__ __launch_bounds__(256) void build_all(
    const float* __restrict__ table,
    unsigned int* __restrict__ rowsH,
    uint4* __restrict__ cellsF)
{
    const int gid = blockIdx.x * 256 + threadIdx.x;
    if (gid < NROWS_L) {
        rowsH[gid] = pack2h(table[2 * gid], table[2 * gid + 1]);
        return;
    }
    const int c = gid - NROWS_L;
    if (c >= NCELLS_F) return;

    int l = 4;
    #pragma unroll
    for (int i = 5; i < 8; ++i) if (c >= CBF[i]) l = i;

    const int cs  = CS[l];
    const int rem = c - CBF[l];
    const int ix  = rem % cs;
    const int t1  = rem / cs;
    const int iy  = t1 % cs;
    const int iz  = t1 / cs;

    const int side  = SIDE[l];
    const int side2 = side * side;
    const int row   = ROWOFF[l] + ix + iy * side + iz * side2;

    unsigned int q[8];
    #pragma unroll
    for (int dz = 0; dz < 2; ++dz) {
        #pragma unroll
        for (int dy = 0; dy < 2; ++dy) {
            const int r = row + dy * side + dz * side2;
            q[(dz * 2 + dy) * 2 + 0] = pack2h(table[2 * r + 0], table[2 * r + 1]);
            q[(dz * 2 + dy) * 2 + 1] = pack2h(table[2 * r + 2], table[2 * r + 3]);
        }
    }
    cellsF[2 * c + 0] = make_uint4(q[0], q[1], q[2], q[3]);
    cellsF[2 * c + 1] = make_uint4(q[4], q[5], q[6], q[7]);
}

// ---- main fused kernel: each block owns a contiguous chunk of points ----
__global__ __launch_bounds__(256, 2) void sdf_main(
    const float* __restrict__ x,
    const unsigned int* __restrict__ rowsH,
    const uint4* __restrict__ cellsF,
    const float* __restrict__ W0,
    const float* __restrict__ W1,
    const float* __restrict__ W2,
    float* __restrict__ out,
    int N, int ptsPerBlock, EncParams ep)
{
    __shared__ __align__(16) unsigned int sRows[NROWS_L];   // 33,412 B
    // packed half2 weights: sW0h[i2*16+j] = {W0[j][2i2], W0[j][2i2+1]}
    __shared__ __align__(16) unsigned int sW0h[128];
    __shared__ __align__(16) unsigned int sW1h[128];
    __shared__ __align__(16) unsigned int sW2h[8];

    const int t = threadIdx.x;
    if (t < 128) {
        const int i2 = t >> 4, j = t & 15;
        sW0h[t] = pack2h(W0[j * 16 + 2 * i2], W0[j * 16 + 2 * i2 + 1]);
    } else {
        const int tt = t - 128;
        const int i2 = tt >> 4, j = tt & 15;
        sW1h[tt] = pack2h(W1[j * 16 + 2 * i2], W1[j * 16 + 2 * i2 + 1]);
    }
    if (t < 8) sW2h[t] = pack2h(W2[2 * t], W2[2 * t + 1]);
    {
        // 8353 = 2088*4 + 1; coalesced uint4 fill (ONCE per block)
        uint4* s4 = reinterpret_cast<uint4*>(sRows);
        const uint4* g4 = reinterpret_cast<const uint4*>(rowsH);
        for (int i = t; i < NROWS_L / 4; i += 256) s4[i] = g4[i];
        if (t == 0) sRows[NROWS_L - 1] = rowsH[NROWS_L - 1];
    }
    __syncthreads();

    const int base = blockIdx.x * ptsPerBlock;

    for (int it = 0; it < ptsPerBlock; it += 256) {
        const int gid = base + it + t;
        if (gid >= N) break;

        const float px = __builtin_nontemporal_load(x + 3 * gid + 0);
        const float py = __builtin_nontemporal_load(x + 3 * gid + 1);
        const float pz = __builtin_nontemporal_load(x + 3 * gid + 2);

        // ---- phase A: fp16 fracs + float-fma indices for all 8 levels ----
        h2 rrx[8], rry[8], rrz[8];
        int rbase[4];   // levels 0..3: row index into sRows
        int cidx[4];    // levels 4..7: cell index into cellsF
        #pragma unroll
        for (int l = 0; l < 8; ++l) {
            const float s = ep.scale[l];
            const float fx = fmaf(px, s, 0.5f);
            const float fy = fmaf(py, s, 0.5f);
            const float fz = fmaf(pz, s, 0.5f);
            const float gx = floorf(fx), gy = floorf(fy), gz = floorf(fz);
            rrx[l] = pkrtz(fx - gx, fx - gx);
            rry[l] = pkrtz(fy - gy, fy - gy);
            rrz[l] = pkrtz(fz - gz, fz - gz);
            if (l < 4) {
                const float rf = fmaf(gz, (float)(SIDE[l] * SIDE[l]),
                                 fmaf(gy, (float)SIDE[l],
                                      gx + (float)ROWOFF[l]));
                rbase[l] = (int)rf;
            } else {
                const float cf = fmaf(gz, (float)(CS[l] * CS[l]),
                                 fmaf(gy, (float)CS[l],
                                      gx + (float)CBF[l]));
                cidx[l - 4] = (int)cf;
            }
        }

        // ---- phase B: issue all 8 fine-level loads (ILP) ----
        uint4 qa[4], qb[4];
        #pragma unroll
        for (int k = 0; k < 4; ++k) {
            const uint4* cp = cellsF + 2 * cidx[k];
            qa[k] = cp[0];
            qb[k] = cp[1];
        }

        h2 feat[8];   // per-level 2-dim features, kept fp16

        // ---- phase C1: levels 0..3 from LDS (overlaps global loads) ----
        #pragma unroll
        for (int l = 0; l < 4; ++l) {
            const int side = SIDE[l], side2 = side * side;
            const int r00 = rbase[l];
            const int r01 = r00 + side;
            const int r10 = r00 + side2;
            const int r11 = r10 + side;
            const unsigned int a00 = sRows[r00], a01 = sRows[r00 + 1];
            const unsigned int b00 = sRows[r01], b01 = sRows[r01 + 1];
            const unsigned int c00 = sRows[r10], c01 = sRows[r10 + 1];
            const unsigned int d00 = sRows[r11], d01 = sRows[r11 + 1];
            const h2 v00 = lerp_h2(as_h2(a00), as_h2(a01), rrx[l]);
            const h2 v01 = lerp_h2(as_h2(b00), as_h2(b01), rrx[l]);
            const h2 v10 = lerp_h2(as_h2(c00), as_h2(c01), rrx[l]);
            const h2 v11 = lerp_h2(as_h2(d00), as_h2(d01), rrx[l]);
            const h2 v0  = lerp_h2(v00, v01, rry[l]);
            const h2 v1  = lerp_h2(v10, v11, rry[l]);
            feat[l] = lerp_h2(v0, v1, rrz[l]);
        }

        // ---- phase C2: levels 4..7 from the fp16 cell array ----
        #pragma unroll
        for (int k = 0; k < 4; ++k) {
            const int l = k + 4;
            const h2 v00 = lerp_h2(as_h2(qa[k].x), as_h2(qa[k].y), rrx[l]);
            const h2 v01 = lerp_h2(as_h2(qa[k].z), as_h2(qa[k].w), rrx[l]);
            const h2 v10 = lerp_h2(as_h2(qb[k].x), as_h2(qb[k].y), rrx[l]);
            const h2 v11 = lerp_h2(as_h2(qb[k].z), as_h2(qb[k].w), rrx[l]);
            const h2 v0  = lerp_h2(v00, v01, rry[l]);
            const h2 v1  = lerp_h2(v10, v11, rry[l]);
            feat[l] = lerp_h2(v0, v1, rrz[l]);
        }

        // ---- MLP: fp16 weights, v_dot2_f32_f16, f32 accumulate ----
        float acc[16];
        #pragma unroll
        for (int j = 0; j < 16; ++j) acc[j] = 0.0f;
        #pragma unroll
        for (int i2 = 0; i2 < 8; ++i2) {
            const h2 f = feat[i2];
            const uint4* wr = reinterpret_cast<const uint4*>(&sW0h[i2 * 16]);
            #pragma unroll
            for (int q = 0; q < 4; ++q) {
                const uint4 w = wr[q];
                acc[4 * q + 0] = dot2f(f, as_h2(w.x), acc[4 * q + 0]);
                acc[4 * q + 1] = dot2f(f, as_h2(w.y), acc[4 * q + 1]);
                acc[4 * q + 2] = dot2f(f, as_h2(w.z), acc[4 * q + 2]);
                acc[4 * q + 3] = dot2f(f, as_h2(w.w), acc[4 * q + 3]);
            }
        }
        h2 hb[8];
        #pragma unroll
        for (int j2 = 0; j2 < 8; ++j2)
            hb[j2] = pkrtz(fmaxf(acc[2 * j2], 0.0f), fmaxf(acc[2 * j2 + 1], 0.0f));

        #pragma unroll
        for (int j = 0; j < 16; ++j) acc[j] = 0.0f;
        #pragma unroll
        for (int i2 = 0; i2 < 8; ++i2) {
            const h2 f = hb[i2];
            const uint4* wr = reinterpret_cast<const uint4*>(&sW1h[i2 * 16]);
            #pragma unroll
            for (int q = 0; q < 4; ++q) {
                const uint4 w = wr[q];
                acc[4 * q + 0] = dot2f(f, as_h2(w.x), acc[4 * q + 0]);
                acc[4 * q + 1] = dot2f(f, as_h2(w.y), acc[4 * q + 1]);
                acc[4 * q + 2] = dot2f(f, as_h2(w.z), acc[4 * q + 2]);
                acc[4 * q + 3] = dot2f(f, as_h2(w.w), acc[4 * q + 3]);
            }
        }
        float o = 0.0f;
        #pragma unroll
        for (int j2 = 0; j2 < 8; ++j2) {
            const h2 f = pkrtz(fmaxf(acc[2 * j2], 0.0f), fmaxf(acc[2 * j2 + 1], 0.0f));
            o = dot2f(f, as_h2(sW2h[j2]), o);
        }
        __builtin_nontemporal_store(o, out + gid);
    }
}

// ---- fallback: direct f32 row-major gather, if ws too small ----
__global__ __launch_bounds__(256) void sdf_fused_fallback(
    const float* __restrict__ x,
    const float* __restrict__ table,
    const float* __restrict__ W0,
    const float* __restrict__ W1,
    const float* __restrict__ W2,
    float* __restrict__ out,
    int N, EncParams ep)
{
    __shared__ __align__(16) float sW0t[256];
    __shared__ __align__(16) float sW1t[256];
    __shared__ __align__(16) float sW2[16];

    const int t = threadIdx.x;
    sW0t[(t & 15) * 16 + (t >> 4)] = W0[t];
    sW1t[(t & 15) * 16 + (t >> 4)] = W1[t];
    if (t < 16) sW2[t] = W2[t];
    __syncthreads();

    const int gid = blockIdx.x * 256 + t;
    if (gid >= N) return;

    const float px = x[3 * gid + 0];
    const float py = x[3 * gid + 1];
    const float pz = x[3 * gid + 2];

    v2f hl[8];
    #pragma unroll
    for (int l = 0; l < 8; ++l) {
        const int side  = SIDE[l];
        const int side2 = side * side;
        const float s = ep.scale[l];
        const float fx = px * s + 0.5f;
        const float fy = py * s + 0.5f;
        const float fz = pz * s + 0.5f;
        const float gx = floorf(fx), gy = floorf(fy), gz = floorf(fz);
        const float rx = fx - gx, ry = fy - gy, rz = fz - gz;
        const int ix = (int)gx, iy = (int)gy, iz = (int)gz;
        const int base = ROWOFF[l] + ix + iy * side + iz * side2;
        const float wx0 = 1.0f - rx, wy0 = 1.0f - ry, wz0 = 1.0f - rz;

        v2f acc = {0.0f, 0.0f};
        #pragma unroll
        for (int dz = 0; dz < 2; ++dz) {
            const float wz = dz ? rz : wz0;
            #pragma unroll
            for (int dy = 0; dy < 2; ++dy) {
                const float wyz = (dy ? ry : wy0) * wz;
                const int r = base + dy * side + dz * side2;
                const float4 f = *reinterpret_cast<const float4*>(table + 2 * r);
                acc += (wyz * wx0) * (v2f){f.x, f.y}
                     + (wyz * rx)  * (v2f){f.z, f.w};
            }
        }
        hl[l] = acc;
    }

    v2f a[8];
    #pragma unroll
    for (int j = 0; j < 8; ++j) a[j] = (v2f){0.0f, 0.0f};
    #pragma unroll
    for (int i2 = 0; i2 < 8; ++i2) {
        const float h0 = hl[i2].x;
        const float h1 = hl[i2].y;
        const float4* w0 = reinterpret_cast<const float4*>(&sW0t[(2 * i2) * 16]);
        const float4* w1 = reinterpret_cast<const float4*>(&sW0t[(2 * i2 + 1) * 16]);
        #pragma unroll
        for (int q = 0; q < 4; ++q) {
            const float4 wa = w0[q];
            const float4 wb = w1[q];
            a[2 * q]     += h0 * (v2f){wa.x, wa.y} + h1 * (v2f){wb.x, wb.y};
            a[2 * q + 1] += h0 * (v2f){wa.z, wa.w} + h1 * (v2f){wb.z, wb.w};
        }
    }
    const v2f zz = {0.0f, 0.0f};
    v2f h1v[8];
    #pragma unroll
    for (int j = 0; j < 8; ++j) h1v[j] = __builtin_elementwise_max(a[j], zz);

    #pragma unroll
    for (int j = 0; j < 8; ++j) a[j] = (v2f){0.0f, 0.0f};
    #pragma unroll
    for (int i2 = 0; i2 < 8; ++i2) {
        const float h0 = h1v[i2].x;
        const float h1 = h1v[i2].y;
        const float4* w0 = reinterpret_cast<const float4*>(&sW1t[(2 * i2) * 16]);
        const float4* w1 = reinterpret_cast<const float4*>(&sW1t[(2 * i2 + 1) * 16]);
        #pragma unroll
        for (int q = 0; q < 4; ++q) {
            const float4 wa = w0[q];
            const float4 wb = w1[q];
            a[2 * q]     += h0 * (v2f){wa.x, wa.y} + h1 * (v2f){wb.x, wb.y};
            a[2 * q + 1] += h0 * (v2f){wa.z, wa.w} + h1 * (v2f){wb.z, wb.w};
        }
    }

    v2f acco = {0.0f, 0.0f};
    #pragma unroll
    for (int j = 0; j < 8; ++j) {
        const v2f h2v = __builtin_elementwise_max(a[j], zz);
        acco += h2v * (v2f){sW2[2 * j], sW2[2 * j + 1]};
    }
    out[gid] = acco.x + acco.y;
}

extern "C" void kernel_launch(void* const* d_in, const int* in_sizes, int n_in,
                              void* d_out, int out_size, void* d_ws, size_t ws_size,
                              hipStream_t stream) {
    const float* x     = (const float*)d_in[0];
    const float* table = (const float*)d_in[1];
    const float* W0    = (const float*)d_in[2];
    const float* W1    = (const float*)d_in[3];
    const float* W2    = (const float*)d_in[4];
    float* out = (float*)d_out;

    const int N = in_sizes[0] / 3;

    EncParams ep;
    const double g = pow(4.0, 1.0 / 7.0);
    for (int l = 0; l < 8; ++l) {
        ep.scale[l] = (float)(8.0 * pow(g, (double)l) - 1.0);
    }

    const size_t rowsBytes = (size_t)NROWS_L * 4;               // 33,412
    const size_t cellsOff  = (rowsBytes + 255) & ~(size_t)255;  // 16B-aligned
    const size_t needBytes = cellsOff + (size_t)NCELLS_F * 32;

    if (ws_size >= needBytes) {
        unsigned int* rowsH = (unsigned int*)d_ws;
        uint4* cellsF = (uint4*)((char*)d_ws + cellsOff);
        const int buildThreads = NROWS_L + NCELLS_F;
        hipLaunchKernelGGL(build_all, dim3((buildThreads + 255) / 256), dim3(256),
                           0, stream, table, rowsH, cellsF);

        // chunked-persistent: 2048 blocks, each owns a contiguous chunk
        int nBlocks = 2048;
        const int maxBlocks = (N + 255) / 256;
        if (nBlocks > maxBlocks) nBlocks = maxBlocks;
        int ptsPerBlock = (N + nBlocks - 1) / nBlocks;
        ptsPerBlock = (ptsPerBlock + 255) & ~255;               // multiple of 256

        hipLaunchKernelGGL(sdf_main, dim3(nBlocks), dim3(256), 0, stream,
                           x, rowsH, cellsF, W0, W1, W2, out, N, ptsPerBlock, ep);
    } else {
        const int blocks = (N + 255) / 256;
        hipLaunchKernelGGL(sdf_fused_fallback, dim3(blocks), dim3(256), 0, stream,
                           x, table, W0, W1, W2, out, N, ep);
    }
}

// Round 14
// 108.152 us; speedup vs baseline: 3.7542x; 3.7542x over previous
//
#include <hip/hip_runtime.h>
#include <math.h>

// Round 14: revert r13's spilling persistent loop (VGPR 128, 891MB scratch
// traffic, 406us). Back to r12's proven body (125.3us), but with 512-thread
// blocks: one point per thread, no loop -> no new live state, but the 33.4KB
// per-block LDS row fill is amortized over 2x the points (16384 -> 8192
// blocks; fill L2 re-reads 547 -> 274MB). launch_bounds(512,2): VGPR cap 256,
// demand ~52.
// Body = fp16 rows L0-3 in LDS + fp16 cells L4-7 + pk-fp16 lerp + dot2 MLP.

typedef float    v2f __attribute__((ext_vector_type(2)));
typedef _Float16 h2  __attribute__((ext_vector_type(2)));
typedef __fp16   hf2 __attribute__((ext_vector_type(2)));   // builtin ABI type

struct EncParams { float scale[8]; };

__constant__ constexpr int SIDE[8]   = {9, 11, 13, 16, 19, 23, 28, 33};
__constant__ constexpr int ROWOFF[8] = {0, 729, 2060, 4257, 8353, 15212, 27379, 49331};
__constant__ constexpr int CS[8]     = {8, 10, 12, 15, 18, 22, 27, 32};
// fine-level cell bases, rebased to 0 at level 4
__constant__ constexpr int CBF[8]    = {0, 0, 0, 0, 0, 5832, 16480, 36163};
#define NROWS_L  8353    // rows of levels 0..3 (= ROWOFF[4]); 33,412 B in LDS
#define NCELLS_F 68931   // cells of levels 4..7

__device__ __forceinline__ unsigned int pack2h(float a, float b) {
    _Float16 ha = (_Float16)a, hb = (_Float16)b;
    unsigned short ua = __builtin_bit_cast(unsigned short, ha);
    unsigned short ub = __builtin_bit_cast(unsigned short, hb);
    return (unsigned int)ua | ((unsigned int)ub << 16);
}
__device__ __forceinline__ h2 as_h2(unsigned int u) {
    return __builtin_bit_cast(h2, u);
}
__device__ __forceinline__ h2 lerp_h2(h2 a, h2 b, h2 r) {
    return a + r * (b - a);   // v_pk_sub/fma_f16
}
__device__ __forceinline__ h2 pkrtz(float a, float b) {
#if __has_builtin(__builtin_amdgcn_cvt_pkrtz)
    return __builtin_bit_cast(h2, __builtin_amdgcn_cvt_pkrtz(a, b));  // 1 op
#else
    return (h2){(_Float16)a, (_Float16)b};
#endif
}
__device__ __forceinline__ float dot2f(h2 a, h2 b, float c) {
#if __has_builtin(__builtin_amdgcn_fdot2)
    return __builtin_amdgcn_fdot2(__builtin_bit_cast(hf2, a),
                                  __builtin_bit_cast(hf2, b), c, false);
#else
    return c + (float)a.x * (float)b.x + (float)a.y * (float)b.y;
#endif
}

// ---- combined build: fp16 rows (levels 0..3) + fp16 cells (levels 4..7) ----
__global__ __launch_bounds__(256) void build_all(
    const float* __restrict__ table,
    unsigned int* __restrict__ rowsH,
    uint4* __restrict__ cellsF)
{
    const int gid = blockIdx.x * 256 + threadIdx.x;
    if (gid < NROWS_L) {
        rowsH[gid] = pack2h(table[2 * gid], table[2 * gid + 1]);
        return;
    }
    const int c = gid - NROWS_L;
    if (c >= NCELLS_F) return;

    int l = 4;
    #pragma unroll
    for (int i = 5; i < 8; ++i) if (c >= CBF[i]) l = i;

    const int cs  = CS[l];
    const int rem = c - CBF[l];
    const int ix  = rem % cs;
    const int t1  = rem / cs;
    const int iy  = t1 % cs;
    const int iz  = t1 / cs;

    const int side  = SIDE[l];
    const int side2 = side * side;
    const int row   = ROWOFF[l] + ix + iy * side + iz * side2;

    unsigned int q[8];
    #pragma unroll
    for (int dz = 0; dz < 2; ++dz) {
        #pragma unroll
        for (int dy = 0; dy < 2; ++dy) {
            const int r = row + dy * side + dz * side2;
            q[(dz * 2 + dy) * 2 + 0] = pack2h(table[2 * r + 0], table[2 * r + 1]);
            q[(dz * 2 + dy) * 2 + 1] = pack2h(table[2 * r + 2], table[2 * r + 3]);
        }
    }
    cellsF[2 * c + 0] = make_uint4(q[0], q[1], q[2], q[3]);
    cellsF[2 * c + 1] = make_uint4(q[4], q[5], q[6], q[7]);
}

// ---- main fused kernel: 512 threads, one point per thread ----
__global__ __launch_bounds__(512, 2) void sdf_main(
    const float* __restrict__ x,
    const unsigned int* __restrict__ rowsH,
    const uint4* __restrict__ cellsF,
    const float* __restrict__ W0,
    const float* __restrict__ W1,
    const float* __restrict__ W2,
    float* __restrict__ out,
    int N, EncParams ep)
{
    __shared__ __align__(16) unsigned int sRows[NROWS_L];   // 33,412 B
    // packed half2 weights: sW0h[i2*16+j] = {W0[j][2i2], W0[j][2i2+1]}
    __shared__ __align__(16) unsigned int sW0h[128];
    __shared__ __align__(16) unsigned int sW1h[128];
    __shared__ __align__(16) unsigned int sW2h[8];

    const int t = threadIdx.x;
    if (t < 128) {
        const int i2 = t >> 4, j = t & 15;
        sW0h[t] = pack2h(W0[j * 16 + 2 * i2], W0[j * 16 + 2 * i2 + 1]);
    } else if (t < 256) {
        const int tt = t - 128;
        const int i2 = tt >> 4, j = tt & 15;
        sW1h[tt] = pack2h(W1[j * 16 + 2 * i2], W1[j * 16 + 2 * i2 + 1]);
    }
    if (t < 8) sW2h[t] = pack2h(W2[2 * t], W2[2 * t + 1]);
    {
        // 8353 = 2088*4 + 1; coalesced uint4 fill
        uint4* s4 = reinterpret_cast<uint4*>(sRows);
        const uint4* g4 = reinterpret_cast<const uint4*>(rowsH);
        for (int i = t; i < NROWS_L / 4; i += 512) s4[i] = g4[i];
        if (t == 0) sRows[NROWS_L - 1] = rowsH[NROWS_L - 1];
    }
    __syncthreads();

    const int gid = blockIdx.x * 512 + t;
    if (gid >= N) return;

    const float px = __builtin_nontemporal_load(x + 3 * gid + 0);
    const float py = __builtin_nontemporal_load(x + 3 * gid + 1);
    const float pz = __builtin_nontemporal_load(x + 3 * gid + 2);

    // ---- phase A: fp16 fracs + float-fma indices for all 8 levels ----
    h2 rrx[8], rry[8], rrz[8];
    int rbase[4];   // levels 0..3: row index into sRows
    int cidx[4];    // levels 4..7: cell index into cellsF
    #pragma unroll
    for (int l = 0; l < 8; ++l) {
        const float s = ep.scale[l];
        const float fx = fmaf(px, s, 0.5f);
        const float fy = fmaf(py, s, 0.5f);
        const float fz = fmaf(pz, s, 0.5f);
        const float gx = floorf(fx), gy = floorf(fy), gz = floorf(fz);
        rrx[l] = pkrtz(fx - gx, fx - gx);
        rry[l] = pkrtz(fy - gy, fy - gy);
        rrz[l] = pkrtz(fz - gz, fz - gz);
        if (l < 4) {
            const float rf = fmaf(gz, (float)(SIDE[l] * SIDE[l]),
                             fmaf(gy, (float)SIDE[l],
                                  gx + (float)ROWOFF[l]));
            rbase[l] = (int)rf;
        } else {
            const float cf = fmaf(gz, (float)(CS[l] * CS[l]),
                             fmaf(gy, (float)CS[l],
                                  gx + (float)CBF[l]));
            cidx[l - 4] = (int)cf;
        }
    }

    // ---- phase B: issue all 8 fine-level loads (ILP) ----
    uint4 qa[4], qb[4];
    #pragma unroll
    for (int k = 0; k < 4; ++k) {
        const uint4* cp = cellsF + 2 * cidx[k];
        qa[k] = cp[0];
        qb[k] = cp[1];
    }

    h2 feat[8];   // per-level 2-dim features, kept fp16

    // ---- phase C1: levels 0..3 from LDS (overlaps global loads) ----
    #pragma unroll
    for (int l = 0; l < 4; ++l) {
        const int side = SIDE[l], side2 = side * side;
        const int r00 = rbase[l];
        const int r01 = r00 + side;
        const int r10 = r00 + side2;
        const int r11 = r10 + side;
        const unsigned int a00 = sRows[r00], a01 = sRows[r00 + 1];
        const unsigned int b00 = sRows[r01], b01 = sRows[r01 + 1];
        const unsigned int c00 = sRows[r10], c01 = sRows[r10 + 1];
        const unsigned int d00 = sRows[r11], d01 = sRows[r11 + 1];
        const h2 v00 = lerp_h2(as_h2(a00), as_h2(a01), rrx[l]);
        const h2 v01 = lerp_h2(as_h2(b00), as_h2(b01), rrx[l]);
        const h2 v10 = lerp_h2(as_h2(c00), as_h2(c01), rrx[l]);
        const h2 v11 = lerp_h2(as_h2(d00), as_h2(d01), rrx[l]);
        const h2 v0  = lerp_h2(v00, v01, rry[l]);
        const h2 v1  = lerp_h2(v10, v11, rry[l]);
        feat[l] = lerp_h2(v0, v1, rrz[l]);
    }

    // ---- phase C2: levels 4..7 from the fp16 cell array ----
    #pragma unroll
    for (int k = 0; k < 4; ++k) {
        const int l = k + 4;
        const h2 v00 = lerp_h2(as_h2(qa[k].x), as_h2(qa[k].y), rrx[l]);
        const h2 v01 = lerp_h2(as_h2(qa[k].z), as_h2(qa[k].w), rrx[l]);
        const h2 v10 = lerp_h2(as_h2(qb[k].x), as_h2(qb[k].y), rrx[l]);
        const h2 v11 = lerp_h2(as_h2(qb[k].z), as_h2(qb[k].w), rrx[l]);
        const h2 v0  = lerp_h2(v00, v01, rry[l]);
        const h2 v1  = lerp_h2(v10, v11, rry[l]);
        feat[l] = lerp_h2(v0, v1, rrz[l]);
    }

    // ---- MLP: fp16 weights, v_dot2_f32_f16, f32 accumulate ----
    float acc[16];
    #pragma unroll
    for (int j = 0; j < 16; ++j) acc[j] = 0.0f;
    #pragma unroll
    for (int i2 = 0; i2 < 8; ++i2) {
        const h2 f = feat[i2];
        const uint4* wr = reinterpret_cast<const uint4*>(&sW0h[i2 * 16]);
        #pragma unroll
        for (int q = 0; q < 4; ++q) {
            const uint4 w = wr[q];
            acc[4 * q + 0] = dot2f(f, as_h2(w.x), acc[4 * q + 0]);
            acc[4 * q + 1] = dot2f(f, as_h2(w.y), acc[4 * q + 1]);
            acc[4 * q + 2] = dot2f(f, as_h2(w.z), acc[4 * q + 2]);
            acc[4 * q + 3] = dot2f(f, as_h2(w.w), acc[4 * q + 3]);
        }
    }
    h2 hb[8];
    #pragma unroll
    for (int j2 = 0; j2 < 8; ++j2)
        hb[j2] = pkrtz(fmaxf(acc[2 * j2], 0.0f), fmaxf(acc[2 * j2 + 1], 0.0f));

    #pragma unroll
    for (int j = 0; j < 16; ++j) acc[j] = 0.0f;
    #pragma unroll
    for (int i2 = 0; i2 < 8; ++i2) {
        const h2 f = hb[i2];
        const uint4* wr = reinterpret_cast<const uint4*>(&sW1h[i2 * 16]);
        #pragma unroll
        for (int q = 0; q < 4; ++q) {
            const uint4 w = wr[q];
            acc[4 * q + 0] = dot2f(f, as_h2(w.x), acc[4 * q + 0]);
            acc[4 * q + 1] = dot2f(f, as_h2(w.y), acc[4 * q + 1]);
            acc[4 * q + 2] = dot2f(f, as_h2(w.z), acc[4 * q + 2]);
            acc[4 * q + 3] = dot2f(f, as_h2(w.w), acc[4 * q + 3]);
        }
    }
    float o = 0.0f;
    #pragma unroll
    for (int j2 = 0; j2 < 8; ++j2) {
        const h2 f = pkrtz(fmaxf(acc[2 * j2], 0.0f), fmaxf(acc[2 * j2 + 1], 0.0f));
        o = dot2f(f, as_h2(sW2h[j2]), o);
    }
    __builtin_nontemporal_store(o, out + gid);
}

// ---- fallback: direct f32 row-major gather, if ws too small ----
__global__ __launch_bounds__(256) void sdf_fused_fallback(
    const float* __restrict__ x,
    const float* __restrict__ table,
    const float* __restrict__ W0,
    const float* __restrict__ W1,
    const float* __restrict__ W2,
    float* __restrict__ out,
    int N, EncParams ep)
{
    __shared__ __align__(16) float sW0t[256];
    __shared__ __align__(16) float sW1t[256];
    __shared__ __align__(16) float sW2[16];

    const int t = threadIdx.x;
    sW0t[(t & 15) * 16 + (t >> 4)] = W0[t];
    sW1t[(t & 15) * 16 + (t >> 4)] = W1[t];
    if (t < 16) sW2[t] = W2[t];
    __syncthreads();

    const int gid = blockIdx.x * 256 + t;
    if (gid >= N) return;

    const float px = x[3 * gid + 0];
    const float py = x[3 * gid + 1];
    const float pz = x[3 * gid + 2];

    v2f hl[8];
    #pragma unroll
    for (int l = 0; l < 8; ++l) {
        const int side  = SIDE[l];
        const int side2 = side * side;
        const float s = ep.scale[l];
        const float fx = px * s + 0.5f;
        const float fy = py * s + 0.5f;
        const float fz = pz * s + 0.5f;
        const float gx = floorf(fx), gy = floorf(fy), gz = floorf(fz);
        const float rx = fx - gx, ry = fy - gy, rz = fz - gz;
        const int ix = (int)gx, iy = (int)gy, iz = (int)gz;
        const int base = ROWOFF[l] + ix + iy * side + iz * side2;
        const float wx0 = 1.0f - rx, wy0 = 1.0f - ry, wz0 = 1.0f - rz;

        v2f acc = {0.0f, 0.0f};
        #pragma unroll
        for (int dz = 0; dz < 2; ++dz) {
            const float wz = dz ? rz : wz0;
            #pragma unroll
            for (int dy = 0; dy < 2; ++dy) {
                const float wyz = (dy ? ry : wy0) * wz;
                const int r = base + dy * side + dz * side2;
                const float4 f = *reinterpret_cast<const float4*>(table + 2 * r);
                acc += (wyz * wx0) * (v2f){f.x, f.y}
                     + (wyz * rx)  * (v2f){f.z, f.w};
            }
        }
        hl[l] = acc;
    }

    v2f a[8];
    #pragma unroll
    for (int j = 0; j < 8; ++j) a[j] = (v2f){0.0f, 0.0f};
    #pragma unroll
    for (int i2 = 0; i2 < 8; ++i2) {
        const float h0 = hl[i2].x;
        const float h1 = hl[i2].y;
        const float4* w0 = reinterpret_cast<const float4*>(&sW0t[(2 * i2) * 16]);
        const float4* w1 = reinterpret_cast<const float4*>(&sW0t[(2 * i2 + 1) * 16]);
        #pragma unroll
        for (int q = 0; q < 4; ++q) {
            const float4 wa = w0[q];
            const float4 wb = w1[q];
            a[2 * q]     += h0 * (v2f){wa.x, wa.y} + h1 * (v2f){wb.x, wb.y};
            a[2 * q + 1] += h0 * (v2f){wa.z, wa.w} + h1 * (v2f){wb.z, wb.w};
        }
    }
    const v2f zz = {0.0f, 0.0f};
    v2f h1v[8];
    #pragma unroll
    for (int j = 0; j < 8; ++j) h1v[j] = __builtin_elementwise_max(a[j], zz);

    #pragma unroll
    for (int j = 0; j < 8; ++j) a[j] = (v2f){0.0f, 0.0f};
    #pragma unroll
    for (int i2 = 0; i2 < 8; ++i2) {
        const float h0 = h1v[i2].x;
        const float h1 = h1v[i2].y;
        const float4* w0 = reinterpret_cast<const float4*>(&sW1t[(2 * i2) * 16]);
        const float4* w1 = reinterpret_cast<const float4*>(&sW1t[(2 * i2 + 1) * 16]);
        #pragma unroll
        for (int q = 0; q < 4; ++q) {
            const float4 wa = w0[q];
            const float4 wb = w1[q];
            a[2 * q]     += h0 * (v2f){wa.x, wa.y} + h1 * (v2f){wb.x, wb.y};
            a[2 * q + 1] += h0 * (v2f){wa.z, wa.w} + h1 * (v2f){wb.z, wb.w};
        }
    }

    v2f acco = {0.0f, 0.0f};
    #pragma unroll
    for (int j = 0; j < 8; ++j) {
        const v2f h2v = __builtin_elementwise_max(a[j], zz);
        acco += h2v * (v2f){sW2[2 * j], sW2[2 * j + 1]};
    }
    out[gid] = acco.x + acco.y;
}

extern "C" void kernel_launch(void* const* d_in, const int* in_sizes, int n_in,
                              void* d_out, int out_size, void* d_ws, size_t ws_size,
                              hipStream_t stream) {
    const float* x     = (const float*)d_in[0];
    const float* table = (const float*)d_in[1];
    const float* W0    = (const float*)d_in[2];
    const float* W1    = (const float*)d_in[3];
    const float* W2    = (const float*)d_in[4];
    float* out = (float*)d_out;

    const int N = in_sizes[0] / 3;

    EncParams ep;
    const double g = pow(4.0, 1.0 / 7.0);
    for (int l = 0; l < 8; ++l) {
        ep.scale[l] = (float)(8.0 * pow(g, (double)l) - 1.0);
    }

    const size_t rowsBytes = (size_t)NROWS_L * 4;               // 33,412
    const size_t cellsOff  = (rowsBytes + 255) & ~(size_t)255;  // 16B-aligned
    const size_t needBytes = cellsOff + (size_t)NCELLS_F * 32;

    if (ws_size >= needBytes) {
        unsigned int* rowsH = (unsigned int*)d_ws;
        uint4* cellsF = (uint4*)((char*)d_ws + cellsOff);
        const int buildThreads = NROWS_L + NCELLS_F;
        hipLaunchKernelGGL(build_all, dim3((buildThreads + 255) / 256), dim3(256),
                           0, stream, table, rowsH, cellsF);
        const int blocks = (N + 511) / 512;
        hipLaunchKernelGGL(sdf_main, dim3(blocks), dim3(512), 0, stream,
                           x, rowsH, cellsF, W0, W1, W2, out, N, ep);
    } else {
        const int blocks = (N + 255) / 256;
        hipLaunchKernelGGL(sdf_fused_fallback, dim3(blocks), dim3(256), 0, stream,
                           x, table, W0, W1, W2, out, N, ep);
    }
}

// Round 15
// 103.868 us; speedup vs baseline: 3.9090x; 1.0412x over previous
//
#include <hip/hip_runtime.h>
#include <math.h>

// Round 15: 1024-thread blocks -- final fill-amortization step.
// R14 (108.2us): VALU 63%, VGPR 36, occ 60%, conflicts 10.4M (~14% of
// cycles), HBM 5%. VALU-only floor ~74us. Remaining cheap lever: halve the
// per-block LDS row-fill count again (8192 -> 4096 fills, fill L2 re-reads
// 274 -> 137MB). 2 blocks/CU x 1024 thr = full 2048 threads, LDS 69.6KB/CU.
// Body byte-identical to r14 (fp16 rows L0-3 LDS + fp16 cells L4-7 +
// pk-fp16 lerp + dot2 MLP). If gain <5%: structural ceiling reached.

typedef float    v2f __attribute__((ext_vector_type(2)));
typedef _Float16 h2  __attribute__((ext_vector_type(2)));
typedef __fp16   hf2 __attribute__((ext_vector_type(2)));   // builtin ABI type

struct EncParams { float scale[8]; };

__constant__ constexpr int SIDE[8]   = {9, 11, 13, 16, 19, 23, 28, 33};
__constant__ constexpr int ROWOFF[8] = {0, 729, 2060, 4257, 8353, 15212, 27379, 49331};
__constant__ constexpr int CS[8]     = {8, 10, 12, 15, 18, 22, 27, 32};
// fine-level cell bases, rebased to 0 at level 4
__constant__ constexpr int CBF[8]    = {0, 0, 0, 0, 0, 5832, 16480, 36163};
#define NROWS_L  8353    // rows of levels 0..3 (= ROWOFF[4]); 33,412 B in LDS
#define NCELLS_F 68931   // cells of levels 4..7

__device__ __forceinline__ unsigned int pack2h(float a, float b) {
    _Float16 ha = (_Float16)a, hb = (_Float16)b;
    unsigned short ua = __builtin_bit_cast(unsigned short, ha);
    unsigned short ub = __builtin_bit_cast(unsigned short, hb);
    return (unsigned int)ua | ((unsigned int)ub << 16);
}
__device__ __forceinline__ h2 as_h2(unsigned int u) {
    return __builtin_bit_cast(h2, u);
}
__device__ __forceinline__ h2 lerp_h2(h2 a, h2 b, h2 r) {
    return a + r * (b - a);   // v_pk_sub/fma_f16
}
__device__ __forceinline__ h2 pkrtz(float a, float b) {
#if __has_builtin(__builtin_amdgcn_cvt_pkrtz)
    return __builtin_bit_cast(h2, __builtin_amdgcn_cvt_pkrtz(a, b));  // 1 op
#else
    return (h2){(_Float16)a, (_Float16)b};
#endif
}
__device__ __forceinline__ float dot2f(h2 a, h2 b, float c) {
#if __has_builtin(__builtin_amdgcn_fdot2)
    return __builtin_amdgcn_fdot2(__builtin_bit_cast(hf2, a),
                                  __builtin_bit_cast(hf2, b), c, false);
#else
    return c + (float)a.x * (float)b.x + (float)a.y * (float)b.y;
#endif
}

// ---- combined build: fp16 rows (levels 0..3) + fp16 cells (levels 4..7) ----
__global__ __launch_bounds__(256) void build_all(
    const float* __restrict__ table,
    unsigned int* __restrict__ rowsH,
    uint4* __restrict__ cellsF)
{
    const int gid = blockIdx.x * 256 + threadIdx.x;
    if (gid < NROWS_L) {
        rowsH[gid] = pack2h(table[2 * gid], table[2 * gid + 1]);
        return;
    }
    const int c = gid - NROWS_L;
    if (c >= NCELLS_F) return;

    int l = 4;
    #pragma unroll
    for (int i = 5; i < 8; ++i) if (c >= CBF[i]) l = i;

    const int cs  = CS[l];
    const int rem = c - CBF[l];
    const int ix  = rem % cs;
    const int t1  = rem / cs;
    const int iy  = t1 % cs;
    const int iz  = t1 / cs;

    const int side  = SIDE[l];
    const int side2 = side * side;
    const int row   = ROWOFF[l] + ix + iy * side + iz * side2;

    unsigned int q[8];
    #pragma unroll
    for (int dz = 0; dz < 2; ++dz) {
        #pragma unroll
        for (int dy = 0; dy < 2; ++dy) {
            const int r = row + dy * side + dz * side2;
            q[(dz * 2 + dy) * 2 + 0] = pack2h(table[2 * r + 0], table[2 * r + 1]);
            q[(dz * 2 + dy) * 2 + 1] = pack2h(table[2 * r + 2], table[2 * r + 3]);
        }
    }
    cellsF[2 * c + 0] = make_uint4(q[0], q[1], q[2], q[3]);
    cellsF[2 * c + 1] = make_uint4(q[4], q[5], q[6], q[7]);
}

// ---- main fused kernel: 1024 threads, one point per thread ----
__global__ __launch_bounds__(1024, 2) void sdf_main(
    const float* __restrict__ x,
    const unsigned int* __restrict__ rowsH,
    const uint4* __restrict__ cellsF,
    const float* __restrict__ W0,
    const float* __restrict__ W1,
    const float* __restrict__ W2,
    float* __restrict__ out,
    int N, EncParams ep)
{
    __shared__ __align__(16) unsigned int sRows[NROWS_L];   // 33,412 B
    // packed half2 weights: sW0h[i2*16+j] = {W0[j][2i2], W0[j][2i2+1]}
    __shared__ __align__(16) unsigned int sW0h[128];
    __shared__ __align__(16) unsigned int sW1h[128];
    __shared__ __align__(16) unsigned int sW2h[8];

    const int t = threadIdx.x;
    if (t < 128) {
        const int i2 = t >> 4, j = t & 15;
        sW0h[t] = pack2h(W0[j * 16 + 2 * i2], W0[j * 16 + 2 * i2 + 1]);
    } else if (t < 256) {
        const int tt = t - 128;
        const int i2 = tt >> 4, j = tt & 15;
        sW1h[tt] = pack2h(W1[j * 16 + 2 * i2], W1[j * 16 + 2 * i2 + 1]);
    }
    if (t < 8) sW2h[t] = pack2h(W2[2 * t], W2[2 * t + 1]);
    {
        // 8353 = 2088*4 + 1; coalesced uint4 fill (once per 1024-thread block)
        uint4* s4 = reinterpret_cast<uint4*>(sRows);
        const uint4* g4 = reinterpret_cast<const uint4*>(rowsH);
        for (int i = t; i < NROWS_L / 4; i += 1024) s4[i] = g4[i];
        if (t == 0) sRows[NROWS_L - 1] = rowsH[NROWS_L - 1];
    }
    __syncthreads();

    const int gid = blockIdx.x * 1024 + t;
    if (gid >= N) return;

    const float px = __builtin_nontemporal_load(x + 3 * gid + 0);
    const float py = __builtin_nontemporal_load(x + 3 * gid + 1);
    const float pz = __builtin_nontemporal_load(x + 3 * gid + 2);

    // ---- phase A: fp16 fracs + float-fma indices for all 8 levels ----
    h2 rrx[8], rry[8], rrz[8];
    int rbase[4];   // levels 0..3: row index into sRows
    int cidx[4];    // levels 4..7: cell index into cellsF
    #pragma unroll
    for (int l = 0; l < 8; ++l) {
        const float s = ep.scale[l];
        const float fx = fmaf(px, s, 0.5f);
        const float fy = fmaf(py, s, 0.5f);
        const float fz = fmaf(pz, s, 0.5f);
        const float gx = floorf(fx), gy = floorf(fy), gz = floorf(fz);
        rrx[l] = pkrtz(fx - gx, fx - gx);
        rry[l] = pkrtz(fy - gy, fy - gy);
        rrz[l] = pkrtz(fz - gz, fz - gz);
        if (l < 4) {
            const float rf = fmaf(gz, (float)(SIDE[l] * SIDE[l]),
                             fmaf(gy, (float)SIDE[l],
                                  gx + (float)ROWOFF[l]));
            rbase[l] = (int)rf;
        } else {
            const float cf = fmaf(gz, (float)(CS[l] * CS[l]),
                             fmaf(gy, (float)CS[l],
                                  gx + (float)CBF[l]));
            cidx[l - 4] = (int)cf;
        }
    }

    // ---- phase B: issue all 8 fine-level loads (ILP) ----
    uint4 qa[4], qb[4];
    #pragma unroll
    for (int k = 0; k < 4; ++k) {
        const uint4* cp = cellsF + 2 * cidx[k];
        qa[k] = cp[0];
        qb[k] = cp[1];
    }

    h2 feat[8];   // per-level 2-dim features, kept fp16

    // ---- phase C1: levels 0..3 from LDS (overlaps global loads) ----
    #pragma unroll
    for (int l = 0; l < 4; ++l) {
        const int side = SIDE[l], side2 = side * side;
        const int r00 = rbase[l];
        const int r01 = r00 + side;
        const int r10 = r00 + side2;
        const int r11 = r10 + side;
        const unsigned int a00 = sRows[r00], a01 = sRows[r00 + 1];
        const unsigned int b00 = sRows[r01], b01 = sRows[r01 + 1];
        const unsigned int c00 = sRows[r10], c01 = sRows[r10 + 1];
        const unsigned int d00 = sRows[r11], d01 = sRows[r11 + 1];
        const h2 v00 = lerp_h2(as_h2(a00), as_h2(a01), rrx[l]);
        const h2 v01 = lerp_h2(as_h2(b00), as_h2(b01), rrx[l]);
        const h2 v10 = lerp_h2(as_h2(c00), as_h2(c01), rrx[l]);
        const h2 v11 = lerp_h2(as_h2(d00), as_h2(d01), rrx[l]);
        const h2 v0  = lerp_h2(v00, v01, rry[l]);
        const h2 v1  = lerp_h2(v10, v11, rry[l]);
        feat[l] = lerp_h2(v0, v1, rrz[l]);
    }

    // ---- phase C2: levels 4..7 from the fp16 cell array ----
    #pragma unroll
    for (int k = 0; k < 4; ++k) {
        const int l = k + 4;
        const h2 v00 = lerp_h2(as_h2(qa[k].x), as_h2(qa[k].y), rrx[l]);
        const h2 v01 = lerp_h2(as_h2(qa[k].z), as_h2(qa[k].w), rrx[l]);
        const h2 v10 = lerp_h2(as_h2(qb[k].x), as_h2(qb[k].y), rrx[l]);
        const h2 v11 = lerp_h2(as_h2(qb[k].z), as_h2(qb[k].w), rrx[l]);
        const h2 v0  = lerp_h2(v00, v01, rry[l]);
        const h2 v1  = lerp_h2(v10, v11, rry[l]);
        feat[l] = lerp_h2(v0, v1, rrz[l]);
    }

    // ---- MLP: fp16 weights, v_dot2_f32_f16, f32 accumulate ----
    float acc[16];
    #pragma unroll
    for (int j = 0; j < 16; ++j) acc[j] = 0.0f;
    #pragma unroll
    for (int i2 = 0; i2 < 8; ++i2) {
        const h2 f = feat[i2];
        const uint4* wr = reinterpret_cast<const uint4*>(&sW0h[i2 * 16]);
        #pragma unroll
        for (int q = 0; q < 4; ++q) {
            const uint4 w = wr[q];
            acc[4 * q + 0] = dot2f(f, as_h2(w.x), acc[4 * q + 0]);
            acc[4 * q + 1] = dot2f(f, as_h2(w.y), acc[4 * q + 1]);
            acc[4 * q + 2] = dot2f(f, as_h2(w.z), acc[4 * q + 2]);
            acc[4 * q + 3] = dot2f(f, as_h2(w.w), acc[4 * q + 3]);
        }
    }
    h2 hb[8];
    #pragma unroll
    for (int j2 = 0; j2 < 8; ++j2)
        hb[j2] = pkrtz(fmaxf(acc[2 * j2], 0.0f), fmaxf(acc[2 * j2 + 1], 0.0f));

    #pragma unroll
    for (int j = 0; j < 16; ++j) acc[j] = 0.0f;
    #pragma unroll
    for (int i2 = 0; i2 < 8; ++i2) {
        const h2 f = hb[i2];
        const uint4* wr = reinterpret_cast<const uint4*>(&sW1h[i2 * 16]);
        #pragma unroll
        for (int q = 0; q < 4; ++q) {
            const uint4 w = wr[q];
            acc[4 * q + 0] = dot2f(f, as_h2(w.x), acc[4 * q + 0]);
            acc[4 * q + 1] = dot2f(f, as_h2(w.y), acc[4 * q + 1]);
            acc[4 * q + 2] = dot2f(f, as_h2(w.z), acc[4 * q + 2]);
            acc[4 * q + 3] = dot2f(f, as_h2(w.w), acc[4 * q + 3]);
        }
    }
    float o = 0.0f;
    #pragma unroll
    for (int j2 = 0; j2 < 8; ++j2) {
        const h2 f = pkrtz(fmaxf(acc[2 * j2], 0.0f), fmaxf(acc[2 * j2 + 1], 0.0f));
        o = dot2f(f, as_h2(sW2h[j2]), o);
    }
    __builtin_nontemporal_store(o, out + gid);
}

// ---- fallback: direct f32 row-major gather, if ws too small ----
__global__ __launch_bounds__(256) void sdf_fused_fallback(
    const float* __restrict__ x,
    const float* __restrict__ table,
    const float* __restrict__ W0,
    const float* __restrict__ W1,
    const float* __restrict__ W2,
    float* __restrict__ out,
    int N, EncParams ep)
{
    __shared__ __align__(16) float sW0t[256];
    __shared__ __align__(16) float sW1t[256];
    __shared__ __align__(16) float sW2[16];

    const int t = threadIdx.x;
    sW0t[(t & 15) * 16 + (t >> 4)] = W0[t];
    sW1t[(t & 15) * 16 + (t >> 4)] = W1[t];
    if (t < 16) sW2[t] = W2[t];
    __syncthreads();

    const int gid = blockIdx.x * 256 + t;
    if (gid >= N) return;

    const float px = x[3 * gid + 0];
    const float py = x[3 * gid + 1];
    const float pz = x[3 * gid + 2];

    v2f hl[8];
    #pragma unroll
    for (int l = 0; l < 8; ++l) {
        const int side  = SIDE[l];
        const int side2 = side * side;
        const float s = ep.scale[l];
        const float fx = px * s + 0.5f;
        const float fy = py * s + 0.5f;
        const float fz = pz * s + 0.5f;
        const float gx = floorf(fx), gy = floorf(fy), gz = floorf(fz);
        const float rx = fx - gx, ry = fy - gy, rz = fz - gz;
        const int ix = (int)gx, iy = (int)gy, iz = (int)gz;
        const int base = ROWOFF[l] + ix + iy * side + iz * side2;
        const float wx0 = 1.0f - rx, wy0 = 1.0f - ry, wz0 = 1.0f - rz;

        v2f acc = {0.0f, 0.0f};
        #pragma unroll
        for (int dz = 0; dz < 2; ++dz) {
            const float wz = dz ? rz : wz0;
            #pragma unroll
            for (int dy = 0; dy < 2; ++dy) {
                const float wyz = (dy ? ry : wy0) * wz;
                const int r = base + dy * side + dz * side2;
                const float4 f = *reinterpret_cast<const float4*>(table + 2 * r);
                acc += (wyz * wx0) * (v2f){f.x, f.y}
                     + (wyz * rx)  * (v2f){f.z, f.w};
            }
        }
        hl[l] = acc;
    }

    v2f a[8];
    #pragma unroll
    for (int j = 0; j < 8; ++j) a[j] = (v2f){0.0f, 0.0f};
    #pragma unroll
    for (int i2 = 0; i2 < 8; ++i2) {
        const float h0 = hl[i2].x;
        const float h1 = hl[i2].y;
        const float4* w0 = reinterpret_cast<const float4*>(&sW0t[(2 * i2) * 16]);
        const float4* w1 = reinterpret_cast<const float4*>(&sW0t[(2 * i2 + 1) * 16]);
        #pragma unroll
        for (int q = 0; q < 4; ++q) {
            const float4 wa = w0[q];
            const float4 wb = w1[q];
            a[2 * q]     += h0 * (v2f){wa.x, wa.y} + h1 * (v2f){wb.x, wb.y};
            a[2 * q + 1] += h0 * (v2f){wa.z, wa.w} + h1 * (v2f){wb.z, wb.w};
        }
    }
    const v2f zz = {0.0f, 0.0f};
    v2f h1v[8];
    #pragma unroll
    for (int j = 0; j < 8; ++j) h1v[j] = __builtin_elementwise_max(a[j], zz);

    #pragma unroll
    for (int j = 0; j < 8; ++j) a[j] = (v2f){0.0f, 0.0f};
    #pragma unroll
    for (int i2 = 0; i2 < 8; ++i2) {
        const float h0 = h1v[i2].x;
        const float h1 = h1v[i2].y;
        const float4* w0 = reinterpret_cast<const float4*>(&sW1t[(2 * i2) * 16]);
        const float4* w1 = reinterpret_cast<const float4*>(&sW1t[(2 * i2 + 1) * 16]);
        #pragma unroll
        for (int q = 0; q < 4; ++q) {
            const float4 wa = w0[q];
            const float4 wb = w1[q];
            a[2 * q]     += h0 * (v2f){wa.x, wa.y} + h1 * (v2f){wb.x, wb.y};
            a[2 * q + 1] += h0 * (v2f){wa.z, wa.w} + h1 * (v2f){wb.z, wb.w};
        }
    }

    v2f acco = {0.0f, 0.0f};
    #pragma unroll
    for (int j = 0; j < 8; ++j) {
        const v2f h2v = __builtin_elementwise_max(a[j], zz);
        acco += h2v * (v2f){sW2[2 * j], sW2[2 * j + 1]};
    }
    out[gid] = acco.x + acco.y;
}

extern "C" void kernel_launch(void* const* d_in, const int* in_sizes, int n_in,
                              void* d_out, int out_size, void* d_ws, size_t ws_size,
                              hipStream_t stream) {
    const float* x     = (const float*)d_in[0];
    const float* table = (const float*)d_in[1];
    const float* W0    = (const float*)d_in[2];
    const float* W1    = (const float*)d_in[3];
    const float* W2    = (const float*)d_in[4];
    float* out = (float*)d_out;

    const int N = in_sizes[0] / 3;

    EncParams ep;
    const double g = pow(4.0, 1.0 / 7.0);
    for (int l = 0; l < 8; ++l) {
        ep.scale[l] = (float)(8.0 * pow(g, (double)l) - 1.0);
    }

    const size_t rowsBytes = (size_t)NROWS_L * 4;               // 33,412
    const size_t cellsOff  = (rowsBytes + 255) & ~(size_t)255;  // 16B-aligned
    const size_t needBytes = cellsOff + (size_t)NCELLS_F * 32;

    if (ws_size >= needBytes) {
        unsigned int* rowsH = (unsigned int*)d_ws;
        uint4* cellsF = (uint4*)((char*)d_ws + cellsOff);
        const int buildThreads = NROWS_L + NCELLS_F;
        hipLaunchKernelGGL(build_all, dim3((buildThreads + 255) / 256), dim3(256),
                           0, stream, table, rowsH, cellsF);
        const int blocks = (N + 1023) / 1024;
        hipLaunchKernelGGL(sdf_main, dim3(blocks), dim3(1024), 0, stream,
                           x, rowsH, cellsF, W0, W1, W2, out, N, ep);
    } else {
        const int blocks = (N + 255) / 256;
        hipLaunchKernelGGL(sdf_fused_fallback, dim3(blocks), dim3(256), 0, stream,
                           x, table, W0, W1, W2, out, N, ep);
    }
}